// Round 2
// baseline (401.328 us; speedup 1.0000x reference)
//
#include <hip/hip_runtime.h>
#include <hip/hip_bf16.h>
#include <math.h>

#define CLASSNUM 70722
#define BATCH 512
#define EMBD 512
#define M_C 0.4f
#define H_C 0.333f
#define S_C 64.0f
#define EPS_C 0.001f
#define PI_F 3.14159265358979f

typedef __bf16 bf16_t;
typedef __bf16 bf16x8 __attribute__((ext_vector_type(8)));
typedef float f32x4 __attribute__((ext_vector_type(4)));

__device__ __forceinline__ float clampf(float x, float lo, float hi) {
    return fminf(fmaxf(x, lo), hi);
}

// async global->LDS, 16 B per lane. LDS dest is wave-uniform base + lane*16.
__device__ __forceinline__ void async_copy16(const bf16_t* g, bf16_t* l) {
    __builtin_amdgcn_global_load_lds(
        (const __attribute__((address_space(1))) unsigned int*)g,
        (__attribute__((address_space(3))) unsigned int*)l, 16, 0, 0);
}

// ---------------------------------------------------------------------------
// prep: block 0 computes margin_scaler ms[512]; blocks 1..256 convert the
// embeddings (A) to bf16 in workspace, PRE-TILED as [kt][512][32] bf16 so
// each GEMM K-step's A tile is one contiguous 32 KB slab (global_load_lds
// requires lane-contiguous global + LDS).
// ---------------------------------------------------------------------------
__global__ __launch_bounds__(256) void prep_kernel(
    const float* __restrict__ emb, const float* __restrict__ norms,
    const float* __restrict__ csn, bf16_t* __restrict__ Aws,
    float* __restrict__ msw)
{
    __shared__ float sred[256];
    const int tid = threadIdx.x;
    if (blockIdx.x == 0) {
        float s0, s1;
        {
            float sn = clampf(norms[tid], 0.001f, 100.0f);
            sn = sn / (csn[tid] + 0.001f);
            s0 = clampf(sn, 0.001f, 100.0f);
        }
        {
            float sn = clampf(norms[tid + 256], 0.001f, 100.0f);
            sn = sn / (csn[tid + 256] + 0.001f);
            s1 = clampf(sn, 0.001f, 100.0f);
        }
        sred[tid] = s0 + s1;
        __syncthreads();
        for (int off = 128; off > 0; off >>= 1) {
            if (tid < off) sred[tid] += sred[tid + off];
            __syncthreads();
        }
        const float mean = sred[0] * (1.0f / 512.0f);
        __syncthreads();
        const float d0 = s0 - mean, d1 = s1 - mean;
        sred[tid] = d0 * d0 + d1 * d1;
        __syncthreads();
        for (int off = 128; off > 0; off >>= 1) {
            if (tid < off) sred[tid] += sred[tid + off];
            __syncthreads();
        }
        const float stdv = sqrtf(sred[0] * (1.0f / 511.0f));  // ddof=1
        const float inv = 1.0f / (stdv + EPS_C);
        msw[tid]       = clampf(d0 * inv * H_C, -1.0f, 1.0f);
        msw[tid + 256] = clampf(d1 * inv * H_C, -1.0f, 1.0f);
    } else {
        const int f = ((blockIdx.x - 1) * 256 + tid) * 4;   // flat elem idx
        const int m = f >> 9;          // row
        const int k = f & 511;         // col within row
        const int kt = k >> 5, ko = k & 31;   // 4 consecutive stay in one kt
        const float4 v = *(const float4*)(emb + f);
        bf16_t h[4] = {(bf16_t)v.x, (bf16_t)v.y, (bf16_t)v.z, (bf16_t)v.w};
        *(unsigned long long*)(Aws + kt * (512 * 32) + m * 32 + ko) =
            *(unsigned long long*)h;
    }
}

// ---------------------------------------------------------------------------
// lab: one wave per batch row. Exact fp32 dot(emb[b], K[:,label[b]]) + column
// norm, full margin formula -> labout[b]. Keeps arccos out of the bf16 path.
// ---------------------------------------------------------------------------
__global__ __launch_bounds__(64) void lab_kernel(
    const float* __restrict__ emb, const int* __restrict__ label,
    const float* __restrict__ kmat, const float* __restrict__ msw,
    float* __restrict__ labout)
{
    const int b = blockIdx.x;
    const int l = threadIdx.x;
    const int lab = label[b];
    const float* col = kmat + lab;
    const float* e = emb + b * EMBD;
    float dot = 0.0f, ss = 0.0f;
    for (int k = l; k < EMBD; k += 64) {
        const float kv = col[(size_t)k * CLASSNUM];
        const float ev = e[k];
        dot = fmaf(ev, kv, dot);
        ss  = fmaf(kv, kv, ss);
    }
    for (int off = 32; off > 0; off >>= 1) {
        dot += __shfl_down(dot, off);
        ss  += __shfl_down(ss, off);
    }
    if (l == 0) {
        float c = dot / sqrtf(ss);
        c = clampf(c, -1.0f + EPS_C, 1.0f - EPS_C);
        const float msv = msw[b];
        float th = acosf(c) - M_C * msv;
        th = clampf(th, EPS_C, PI_F - EPS_C);
        labout[b] = (cosf(th) - (M_C + M_C * msv)) * S_C;
    }
}

// ---------------------------------------------------------------------------
// gemm: MT=512 (entire batch) x NT=64 per block -> kernel matrix B is read
// from HBM EXACTLY ONCE (no inter-block B reuse needed). 256 threads =
// 4 waves; wave w computes rows [w*128, w*128+128) x all 64 cols via
// 8x4 of mfma_f32_16x16x32_bf16 (acc 128 VGPR).
// Pipeline per K-step (BK=32, 16 steps):
//   barrier -> issue B(it+1) scalar loads (regs), issue A(it+1)
//   global_load_lds into other LDS buffer -> MFMA on current buffers ->
//   convert B(it+1) regs to bf16 (waits vmcnt(8): A stays in flight) ->
//   write Blds[next].
// The barrier's vmcnt(0) drain therefore only waits on loads that had a
// full MFMA phase to complete (fixes the R1 per-iter latency stall).
// ---------------------------------------------------------------------------
__global__ __launch_bounds__(256, 2) void gemm_kernel(
    const bf16_t* __restrict__ Aws, const float* __restrict__ Kmat,
    float* __restrict__ out)
{
    __shared__ bf16_t Alds[2][512 * 32];   // 2 x 32 KB
    __shared__ bf16_t Blds[2][64 * 32];    // 2 x 4 KB
    __shared__ float red[256];
    __shared__ float invn[64];

    const int tid  = threadIdx.x;
    const int lane = tid & 63;
    const int wave = tid >> 6;
    const int quad = lane >> 4;
    const int r16  = lane & 15;
    const int n0   = blockIdx.x * 64;

    // B staging: thread owns (column bc, k-octet bh) for the whole K loop.
    const int bc = tid & 63;
    const int bh = tid >> 6;
    const bool nv = (n0 + bc) < CLASSNUM;
    const float* bp = Kmat + (size_t)(n0 + bc);

    f32x4 acc[8][4];
    const f32x4 zero = {0.0f, 0.0f, 0.0f, 0.0f};
#pragma unroll
    for (int i = 0; i < 8; ++i)
#pragma unroll
        for (int j = 0; j < 4; ++j) acc[i][j] = zero;

    float ssq = 0.0f;
    float bv[8];

    // ---- prologue: B(0) regs, A(0) async, B(0) -> Blds[0] ----
#pragma unroll
    for (int j = 0; j < 8; ++j)
        bv[j] = nv ? bp[(size_t)(bh * 8 + j) * CLASSNUM] : 0.0f;
#pragma unroll
    for (int i = 0; i < 8; ++i)
        async_copy16(Aws + i * 2048 + wave * 512 + lane * 8,
                     &Alds[0][i * 2048 + wave * 512]);
    {
        bf16x8 bw;
#pragma unroll
        for (int j = 0; j < 8; ++j) {
            const float v = bv[j];
            ssq = fmaf(v, v, ssq);
            bw[j] = (bf16_t)v;
        }
        *(bf16x8*)&Blds[0][bc * 32 + bh * 8] = bw;
    }

    for (int it = 0; it < 16; ++it) {
        const int buf = it & 1;
        __syncthreads();   // drains A(it) async copies; Blds[buf] writes visible

        if (it < 15) {
            // B(it+1) first (older in vmcnt queue), then A(it+1) async.
            const size_t kb = (size_t)((it + 1) * 32 + bh * 8) * CLASSNUM;
#pragma unroll
            for (int j = 0; j < 8; ++j)
                bv[j] = nv ? bp[kb + (size_t)j * CLASSNUM] : 0.0f;
            const bf16_t* gs = Aws + (size_t)(it + 1) * 16384;
#pragma unroll
            for (int i = 0; i < 8; ++i)
                async_copy16(gs + i * 2048 + wave * 512 + lane * 8,
                             &Alds[buf ^ 1][i * 2048 + wave * 512]);
        }

        // ---- MFMA on Alds[buf] / Blds[buf] ----
        bf16x8 bfr[4];
#pragma unroll
        for (int ni = 0; ni < 4; ++ni)
            bfr[ni] = *(const bf16x8*)&Blds[buf][(ni * 16 + r16) * 32 + quad * 8];
#pragma unroll
        for (int mi = 0; mi < 8; ++mi) {
            const bf16x8 af = *(const bf16x8*)
                &Alds[buf][(wave * 128 + mi * 16 + r16) * 32 + quad * 8];
#pragma unroll
            for (int ni = 0; ni < 4; ++ni)
                acc[mi][ni] = __builtin_amdgcn_mfma_f32_16x16x32_bf16(
                    af, bfr[ni], acc[mi][ni], 0, 0, 0);
        }

        if (it < 15) {
            // convert B(it+1) -> Blds[buf^1] (vmcnt(8): A-lds stays in flight)
            bf16x8 bw;
#pragma unroll
            for (int j = 0; j < 8; ++j) {
                const float v = bv[j];
                ssq = fmaf(v, v, ssq);
                bw[j] = (bf16_t)v;
            }
            *(bf16x8*)&Blds[buf ^ 1][bc * 32 + bh * 8] = bw;
        }
    }

    // ---- column inv-norms: reduce the 4 k-partials per column ----
    red[tid] = ssq;
    __syncthreads();
    if (tid < 64) {
        const float s = red[tid] + red[tid + 64] + red[tid + 128] + red[tid + 192];
        invn[tid] = (s > 0.0f) ? (1.0f / sqrtf(s)) : 0.0f;
    }
    __syncthreads();

    // ---- epilogue: out = S * clip(c); label entries overwritten later ----
#pragma unroll
    for (int ni = 0; ni < 4; ++ni) {
        const int col_loc = ni * 16 + r16;
        const int col = n0 + col_loc;
        if (col < CLASSNUM) {
            const float inv = invn[col_loc];
#pragma unroll
            for (int mi = 0; mi < 8; ++mi) {
                const int row = wave * 128 + mi * 16 + quad * 4;
                const f32x4 a = acc[mi][ni];
#pragma unroll
                for (int rr = 0; rr < 4; ++rr) {
                    const float c = clampf(a[rr] * inv, -1.0f + EPS_C, 1.0f - EPS_C);
                    out[(size_t)(row + rr) * CLASSNUM + col] = c * S_C;
                }
            }
        }
    }
}

// ---------------------------------------------------------------------------
// scatter: overwrite the 512 (row, label) entries with the exact fp32 values.
// ---------------------------------------------------------------------------
__global__ __launch_bounds__(512) void scatter_kernel(
    const int* __restrict__ label, const float* __restrict__ labout,
    float* __restrict__ out)
{
    const int t = threadIdx.x;
    out[(size_t)t * CLASSNUM + label[t]] = labout[t];
}

extern "C" void kernel_launch(void* const* d_in, const int* in_sizes, int n_in,
                              void* d_out, int out_size, void* d_ws, size_t ws_size,
                              hipStream_t stream)
{
    const float* emb   = (const float*)d_in[0];
    const float* norms = (const float*)d_in[1];
    const int*   label = (const int*)d_in[2];
    const float* csn   = (const float*)d_in[3];
    const float* kmat  = (const float*)d_in[4];
    float* out = (float*)d_out;

    // workspace layout: [A bf16 tiled 512x512 | ms 512 f32 | labout 512 f32]
    const size_t A_BYTES = (size_t)BATCH * EMBD * sizeof(bf16_t);  // 524288
    if (ws_size < A_BYTES + 4096) return;
    bf16_t* Aws   = (bf16_t*)d_ws;
    float* msw    = (float*)((char*)d_ws + A_BYTES);
    float* labout = (float*)((char*)d_ws + A_BYTES + 2048);

    prep_kernel<<<257, 256, 0, stream>>>(emb, norms, csn, Aws, msw);
    lab_kernel<<<BATCH, 64, 0, stream>>>(emb, label, kmat, msw, labout);
    const int nblk = (CLASSNUM + 63) / 64;   // 1106
    gemm_kernel<<<nblk, 256, 0, stream>>>(Aws, kmat, out);
    scatter_kernel<<<1, 512, 0, stream>>>(label, labout, out);
}

// Round 3
// 364.971 us; speedup vs baseline: 1.0996x; 1.0996x over previous
//
#include <hip/hip_runtime.h>
#include <hip/hip_bf16.h>
#include <math.h>

#define CLASSNUM 70722
#define BATCH 512
#define EMBD 512
#define M_C 0.4f
#define H_C 0.333f
#define S_C 64.0f
#define EPS_C 0.001f
#define PI_F 3.14159265358979f

typedef __bf16 bf16_t;
typedef __bf16 bf16x8 __attribute__((ext_vector_type(8)));
typedef float f32x4 __attribute__((ext_vector_type(4)));

__device__ __forceinline__ float clampf(float x, float lo, float hi) {
    return fminf(fmaxf(x, lo), hi);
}

// async global->LDS, 16 B per lane. LDS dest is wave-uniform base + lane*16.
__device__ __forceinline__ void async_copy16(const bf16_t* g, bf16_t* l) {
    __builtin_amdgcn_global_load_lds(
        (const __attribute__((address_space(1))) unsigned int*)g,
        (__attribute__((address_space(3))) unsigned int*)l, 16, 0, 0);
}

// A LDS/ws layout: per 32-k slab, 16-B granule for (row m, k-octet q) lives at
// granule index m*4 + (q ^ ((m>>1)&3)).  global_load_lds forbids padding, so
// this XOR swizzle is the bank-conflict fix: for a b128 frag read (16 rows,
// fixed q) the bank-quad slot is (m&1)*4 + (q ^ ((m>>1)&3)) -> all 8 slots
// covered, 2-way aliasing only (free per m136). R2's unpadded layout was
// 8-way (2.94x) and LDS-pipe-bound the whole kernel.

// ---------------------------------------------------------------------------
// prep: block 0 computes margin_scaler ms[512]; blocks 1..128 convert the
// embeddings (A) to bf16 in workspace, tiled [kt][granule-swizzled 512x32].
// One thread = one 16-B granule (8 elems).
// ---------------------------------------------------------------------------
__global__ __launch_bounds__(256) void prep_kernel(
    const float* __restrict__ emb, const float* __restrict__ norms,
    const float* __restrict__ csn, bf16_t* __restrict__ Aws,
    float* __restrict__ msw)
{
    __shared__ float sred[256];
    const int tid = threadIdx.x;
    if (blockIdx.x == 0) {
        float s0, s1;
        {
            float sn = clampf(norms[tid], 0.001f, 100.0f);
            sn = sn / (csn[tid] + 0.001f);
            s0 = clampf(sn, 0.001f, 100.0f);
        }
        {
            float sn = clampf(norms[tid + 256], 0.001f, 100.0f);
            sn = sn / (csn[tid + 256] + 0.001f);
            s1 = clampf(sn, 0.001f, 100.0f);
        }
        sred[tid] = s0 + s1;
        __syncthreads();
        for (int off = 128; off > 0; off >>= 1) {
            if (tid < off) sred[tid] += sred[tid + off];
            __syncthreads();
        }
        const float mean = sred[0] * (1.0f / 512.0f);
        __syncthreads();
        const float d0 = s0 - mean, d1 = s1 - mean;
        sred[tid] = d0 * d0 + d1 * d1;
        __syncthreads();
        for (int off = 128; off > 0; off >>= 1) {
            if (tid < off) sred[tid] += sred[tid + off];
            __syncthreads();
        }
        const float stdv = sqrtf(sred[0] * (1.0f / 511.0f));  // ddof=1
        const float inv = 1.0f / (stdv + EPS_C);
        msw[tid]       = clampf(d0 * inv * H_C, -1.0f, 1.0f);
        msw[tid + 256] = clampf(d1 * inv * H_C, -1.0f, 1.0f);
    } else {
        const int G = (blockIdx.x - 1) * 256 + tid;   // granule id, 0..32767
        const int kt = G >> 11;                        // 2048 granules / slab
        const int rem = G & 2047;
        const int m = rem >> 2;
        const int q = rem & 3;
        const int qs = q ^ ((m >> 1) & 3);             // source octet
        const float* src = emb + m * EMBD + kt * 32 + qs * 8;
        const float4 v0 = *(const float4*)src;
        const float4 v1 = *(const float4*)(src + 4);
        bf16x8 bw;
        bw[0] = (bf16_t)v0.x; bw[1] = (bf16_t)v0.y;
        bw[2] = (bf16_t)v0.z; bw[3] = (bf16_t)v0.w;
        bw[4] = (bf16_t)v1.x; bw[5] = (bf16_t)v1.y;
        bw[6] = (bf16_t)v1.z; bw[7] = (bf16_t)v1.w;
        *(bf16x8*)(Aws + (size_t)G * 8) = bw;          // coalesced 16 B store
    }
}

// ---------------------------------------------------------------------------
// lab: one wave per batch row. Exact fp32 dot(emb[b], K[:,label[b]]) + column
// norm, full margin formula -> labout[b]. Keeps arccos out of the bf16 path.
// ---------------------------------------------------------------------------
__global__ __launch_bounds__(64) void lab_kernel(
    const float* __restrict__ emb, const int* __restrict__ label,
    const float* __restrict__ kmat, const float* __restrict__ msw,
    float* __restrict__ labout)
{
    const int b = blockIdx.x;
    const int l = threadIdx.x;
    const int lab = label[b];
    const float* col = kmat + lab;
    const float* e = emb + b * EMBD;
    float dot = 0.0f, ss = 0.0f;
    for (int k = l; k < EMBD; k += 64) {
        const float kv = col[(size_t)k * CLASSNUM];
        const float ev = e[k];
        dot = fmaf(ev, kv, dot);
        ss  = fmaf(kv, kv, ss);
    }
    for (int off = 32; off > 0; off >>= 1) {
        dot += __shfl_down(dot, off);
        ss  += __shfl_down(ss, off);
    }
    if (l == 0) {
        float c = dot / sqrtf(ss);
        c = clampf(c, -1.0f + EPS_C, 1.0f - EPS_C);
        const float msv = msw[b];
        float th = acosf(c) - M_C * msv;
        th = clampf(th, EPS_C, PI_F - EPS_C);
        labout[b] = (cosf(th) - (M_C + M_C * msv)) * S_C;
    }
}

// ---------------------------------------------------------------------------
// gemm: MT=512 (entire batch) x NT=64 per block -> B read from HBM once.
// 256 threads = 4 waves; wave w computes rows [w*128, w*128+128) x 64 cols
// via 8x4 of mfma_f32_16x16x32_bf16. A double-buffered via global_load_lds
// (swizzled granules, conflict-free); B reg-prefetched 1 iter ahead,
// fp32->bf16 converted after the MFMA phase, stored to padded (stride-40)
// Blds. Epilogue stores ni-innermost so 4 consecutive insts cover 256 B
// contiguous per row (write-combining; R2 overshot WRITE by 1.49x).
// ---------------------------------------------------------------------------
__global__ __launch_bounds__(256, 2) void gemm_kernel(
    const bf16_t* __restrict__ Aws, const float* __restrict__ Kmat,
    float* __restrict__ out)
{
    __shared__ bf16_t Alds[2][512 * 32];   // 2 x 32 KB, swizzled granules
    __shared__ bf16_t Blds[2][64 * 40];    // 2 x 5 KB, padded rows
    __shared__ float red[256];
    __shared__ float invn[64];

    const int tid  = threadIdx.x;
    const int lane = tid & 63;
    const int wave = tid >> 6;
    const int quad = lane >> 4;
    const int r16  = lane & 15;
    const int n0   = blockIdx.x * 64;

    // B staging: thread owns (column bc, k-octet bh) for the whole K loop.
    const int bc = tid & 63;
    const int bh = tid >> 6;
    const bool nv = (n0 + bc) < CLASSNUM;
    const float* bp = Kmat + (size_t)(n0 + bc);

    f32x4 acc[8][4];
    const f32x4 zero = {0.0f, 0.0f, 0.0f, 0.0f};
#pragma unroll
    for (int i = 0; i < 8; ++i)
#pragma unroll
        for (int j = 0; j < 4; ++j) acc[i][j] = zero;

    float ssq = 0.0f;
    float bv[8];

    // ---- prologue: B(0) regs, A(0) async, B(0) -> Blds[0] ----
#pragma unroll
    for (int j = 0; j < 8; ++j)
        bv[j] = nv ? bp[(size_t)(bh * 8 + j) * CLASSNUM] : 0.0f;
#pragma unroll
    for (int i = 0; i < 8; ++i)
        async_copy16(Aws + i * 2048 + wave * 512 + lane * 8,
                     &Alds[0][i * 2048 + wave * 512]);
    {
        bf16x8 bw;
#pragma unroll
        for (int j = 0; j < 8; ++j) {
            const float v = bv[j];
            ssq = fmaf(v, v, ssq);
            bw[j] = (bf16_t)v;
        }
        *(bf16x8*)&Blds[0][bc * 40 + bh * 8] = bw;
    }

    for (int it = 0; it < 16; ++it) {
        const int buf = it & 1;
        __syncthreads();   // drains A(it) async copies; Blds[buf] visible

        if (it < 15) {
            // B(it+1) first (older in vmcnt queue), then A(it+1) async.
            const size_t kb = (size_t)((it + 1) * 32 + bh * 8) * CLASSNUM;
#pragma unroll
            for (int j = 0; j < 8; ++j)
                bv[j] = nv ? bp[kb + (size_t)j * CLASSNUM] : 0.0f;
            const bf16_t* gs = Aws + (size_t)(it + 1) * 16384;
#pragma unroll
            for (int i = 0; i < 8; ++i)
                async_copy16(gs + i * 2048 + wave * 512 + lane * 8,
                             &Alds[buf ^ 1][i * 2048 + wave * 512]);
        }

        // ---- MFMA on Alds[buf] / Blds[buf] ----
        bf16x8 bfr[4];
#pragma unroll
        for (int ni = 0; ni < 4; ++ni)
            bfr[ni] = *(const bf16x8*)&Blds[buf][(ni * 16 + r16) * 40 + quad * 8];
#pragma unroll
        for (int mi = 0; mi < 8; ++mi) {
            const int row = wave * 128 + mi * 16 + r16;
            const int swz = (row >> 1) & 3;
            const bf16x8 af = *(const bf16x8*)
                &Alds[buf][row * 32 + ((quad ^ swz) << 3)];
#pragma unroll
            for (int ni = 0; ni < 4; ++ni)
                acc[mi][ni] = __builtin_amdgcn_mfma_f32_16x16x32_bf16(
                    af, bfr[ni], acc[mi][ni], 0, 0, 0);
        }

        if (it < 15) {
            // convert B(it+1) -> Blds[buf^1] (vmcnt(8): A-lds stays in flight)
            bf16x8 bw;
#pragma unroll
            for (int j = 0; j < 8; ++j) {
                const float v = bv[j];
                ssq = fmaf(v, v, ssq);
                bw[j] = (bf16_t)v;
            }
            *(bf16x8*)&Blds[buf ^ 1][bc * 40 + bh * 8] = bw;
        }
    }

    // ---- column inv-norms: reduce the 4 k-partials per column ----
    red[tid] = ssq;
    __syncthreads();
    if (tid < 64) {
        const float s = red[tid] + red[tid + 64] + red[tid + 128] + red[tid + 192];
        invn[tid] = (s > 0.0f) ? (1.0f / sqrtf(s)) : 0.0f;
    }
    __syncthreads();

    // ---- epilogue: out = S * clip(c); label entries overwritten later.
    // ni innermost: 4 consecutive stores cover cols n0..n0+63 (256 B) for
    // each row -> full-line write combining.
#pragma unroll
    for (int mi = 0; mi < 8; ++mi) {
        const int row = wave * 128 + mi * 16 + quad * 4;
#pragma unroll
        for (int rr = 0; rr < 4; ++rr) {
            float* orow = out + (size_t)(row + rr) * CLASSNUM;
#pragma unroll
            for (int ni = 0; ni < 4; ++ni) {
                const int col_loc = ni * 16 + r16;
                const int col = n0 + col_loc;
                if (col < CLASSNUM) {
                    const float c = clampf(acc[mi][ni][rr] * invn[col_loc],
                                           -1.0f + EPS_C, 1.0f - EPS_C);
                    orow[col] = c * S_C;
                }
            }
        }
    }
}

// ---------------------------------------------------------------------------
// scatter: overwrite the 512 (row, label) entries with the exact fp32 values.
// ---------------------------------------------------------------------------
__global__ __launch_bounds__(512) void scatter_kernel(
    const int* __restrict__ label, const float* __restrict__ labout,
    float* __restrict__ out)
{
    const int t = threadIdx.x;
    out[(size_t)t * CLASSNUM + label[t]] = labout[t];
}

extern "C" void kernel_launch(void* const* d_in, const int* in_sizes, int n_in,
                              void* d_out, int out_size, void* d_ws, size_t ws_size,
                              hipStream_t stream)
{
    const float* emb   = (const float*)d_in[0];
    const float* norms = (const float*)d_in[1];
    const int*   label = (const int*)d_in[2];
    const float* csn   = (const float*)d_in[3];
    const float* kmat  = (const float*)d_in[4];
    float* out = (float*)d_out;

    // workspace layout: [A bf16 swizzle-tiled 512x512 | ms 512 | labout 512]
    const size_t A_BYTES = (size_t)BATCH * EMBD * sizeof(bf16_t);  // 524288
    if (ws_size < A_BYTES + 4096) return;
    bf16_t* Aws   = (bf16_t*)d_ws;
    float* msw    = (float*)((char*)d_ws + A_BYTES);
    float* labout = (float*)((char*)d_ws + A_BYTES + 2048);

    prep_kernel<<<129, 256, 0, stream>>>(emb, norms, csn, Aws, msw);
    lab_kernel<<<BATCH, 64, 0, stream>>>(emb, label, kmat, msw, labout);
    const int nblk = (CLASSNUM + 63) / 64;   // 1106
    gemm_kernel<<<nblk, 256, 0, stream>>>(Aws, kmat, out);
    scatter_kernel<<<1, 512, 0, stream>>>(label, labout, out);
}